// Round 7
// baseline (2824.563 us; speedup 1.0000x reference)
//
#include <hip/hip_runtime.h>

// GCN 2-layer forward, N=50000, F=128, E=1.6M (+ self loops).
//
//   h'   = (x @ W^T + b) * dinv[row]        (stored bf16 -> halves gather bytes)
//   out  = dinv[row] * (h'[row] + sum_{e: dst=row} h'[src[e]])   (+ relu L1)
//
// Edges counting-sorted by 64-node dst range, then src-bucket-sorted (src>>8)
// within each range. Aggregation is PUSH into a per-range 64x128 f32 LDS
// accumulator (all 782 blocks co-resident -> synchronized ascending-src sweep
// of hbuf for L2 locality). No global f32 atomics anywhere.
// GEMM: register-tiled VALU SGEMM (no f32 MFMA on CDNA4), bf16 pack epilogue.
//
// ws layout:
//   [0]     rtot    R i32
//   [4K]    rbase   R+1 i32
//   [8K]    gcur    R i32
//   [16K]   dinv    N f32    (200 KB)
//   [1M]    rsorted E u32    (6.4 MB)   packed (dstLocal<<16 | src)
//   [8M]    csr2    E u32    (6.4 MB)   src-bucket-sorted per range
//   [16M]   hbuf    N*F bf16 (12.8 MB)
// d_out doubles as the layer-1 aggregation output (fully overwritten later).

static constexpr int F = 128;
static constexpr int NR = 64;     // nodes per range (dst>>6)
static constexpr int CH = 4096;   // edges per chunk
static constexpr int RMAX = 1024; // max ranges (N <= 65536)

__device__ __forceinline__ unsigned f2b(float x) {  // f32 -> bf16 bits, RNE
  unsigned u = __float_as_uint(x);
  return (u + 0x7fffu + ((u >> 16) & 1u)) >> 16;
}
__device__ __forceinline__ float b_lo(unsigned u) {
  return __uint_as_float(u << 16);
}
__device__ __forceinline__ float b_hi(unsigned u) {
  return __uint_as_float(u & 0xffff0000u);
}

__global__ void k_zero_i32(int* __restrict__ p, int n) {
  int i = blockIdx.x * blockDim.x + threadIdx.x;
  if (i < n) p[i] = 0;
}

__global__ __launch_bounds__(256) void k_hist(const int* __restrict__ dst,
                                              int E, int R,
                                              int* __restrict__ rtot) {
  __shared__ int h[RMAX];
  for (int i = threadIdx.x; i < R; i += 256) h[i] = 0;
  __syncthreads();
  const int e0 = blockIdx.x * CH;
  const int e1 = min(e0 + CH, E);
  for (int i = e0 + threadIdx.x; i < e1; i += 256)
    atomicAdd(&h[dst[i] >> 6], 1);
  __syncthreads();
  for (int i = threadIdx.x; i < R; i += 256)
    if (h[i]) atomicAdd(&rtot[i], h[i]);
}

__global__ __launch_bounds__(1024) void k_scanR(const int* __restrict__ rtot,
                                                int R, int E,
                                                int* __restrict__ rbase,
                                                int* __restrict__ gcur) {
  __shared__ int s[1024];
  const int t = threadIdx.x;
  const int v = (t < R) ? rtot[t] : 0;
  s[t] = v;
  __syncthreads();
#pragma unroll
  for (int off = 1; off < 1024; off <<= 1) {
    int a = (t >= off) ? s[t - off] : 0;
    __syncthreads();
    s[t] += a;
    __syncthreads();
  }
  if (t < R) {
    const int b = s[t] - v;  // exclusive
    rbase[t] = b;
    gcur[t] = b;
  }
  if (t == 0) rbase[R] = E;
}

__global__ __launch_bounds__(256) void k_part(const int* __restrict__ src,
                                              const int* __restrict__ dst,
                                              int E, int R,
                                              int* __restrict__ gcur,
                                              unsigned* __restrict__ rsorted) {
  __shared__ int h[RMAX];
  __shared__ int cur[RMAX];
  for (int i = threadIdx.x; i < R; i += 256) h[i] = 0;
  __syncthreads();
  const int e0 = blockIdx.x * CH;
  const int e1 = min(e0 + CH, E);
  for (int i = e0 + threadIdx.x; i < e1; i += 256)
    atomicAdd(&h[dst[i] >> 6], 1);
  __syncthreads();
  for (int i = threadIdx.x; i < R; i += 256)
    cur[i] = h[i] ? atomicAdd(&gcur[i], h[i]) : 0;
  __syncthreads();
  for (int i = e0 + threadIdx.x; i < e1; i += 256) {
    const int d = dst[i];
    const int s = src[i];
    const int pos = atomicAdd(&cur[d >> 6], 1);
    rsorted[pos] = ((unsigned)(d & (NR - 1)) << 16) | (unsigned)s;
  }
}

// per range: bucket-sort segment by src>>8 (ascending-src sweep order),
// and compute dinv for the range's nodes.
__global__ __launch_bounds__(256) void k_sortR(
    const unsigned* __restrict__ rsorted, const int* __restrict__ rbase,
    int N, float* __restrict__ dinv, unsigned* __restrict__ csr2) {
  __shared__ int h2[256];
  __shared__ int cur2[256];
  __shared__ int dcnt[NR];
  const int r = blockIdx.x;
  const int tid = threadIdx.x;
  const int b = rbase[r];
  const int e = rbase[r + 1];
  h2[tid] = 0;
  if (tid < NR) dcnt[tid] = 0;
  __syncthreads();
  for (int i = b + tid; i < e; i += 256) {
    const unsigned v = rsorted[i];
    atomicAdd(&h2[(v & 0xffffu) >> 8], 1);
    atomicAdd(&dcnt[v >> 16], 1);
  }
  __syncthreads();
  const int c = h2[tid];
  // in-place inclusive scan of h2
#pragma unroll
  for (int off = 1; off < 256; off <<= 1) {
    int a = (tid >= off) ? h2[tid - off] : 0;
    __syncthreads();
    h2[tid] += a;
    __syncthreads();
  }
  cur2[tid] = h2[tid] - c;  // exclusive
  if (tid < NR) {
    const int node = r * NR + tid;
    if (node < N) dinv[node] = rsqrtf((float)(dcnt[tid] + 1));  // +1 self loop
  }
  __syncthreads();
  for (int i = b + tid; i < e; i += 256) {
    const unsigned v = rsorted[i];
    const int pos = b + atomicAdd(&cur2[(v & 0xffffu) >> 8], 1);
    csr2[pos] = v;
  }
}

// hout[m,:] = bf16( (A[m,:] @ W^T + bias) * dinv[m] )
// block tile 64x128, thread micro-tile 8x4, K tiled by 32.
static constexpr int ASTR = 68;   // 64 + 4 pad (keeps 16B alignment)
static constexpr int BSTR = 132;  // 128 + 4 pad

__global__ __launch_bounds__(256) void k_gemm(
    const float* __restrict__ A, const float* __restrict__ W,
    const float* __restrict__ bias, const float* __restrict__ dinv,
    uint2* __restrict__ hout, int n) {
  __shared__ float As[32][ASTR];  // [k][m]  (transposed)
  __shared__ float Bs[32][BSTR];  // [k][n]  (W transposed)
  const int tid = threadIdx.x;
  const int tm = tid >> 5;  // 0..7  -> rows  tm*8 .. tm*8+7
  const int tn = tid & 31;  // 0..31 -> cols  tn*4 .. tn*4+3
  const int m0 = blockIdx.x * 64;

  float acc[8][4];
#pragma unroll
  for (int i = 0; i < 8; ++i)
#pragma unroll
    for (int j = 0; j < 4; ++j) acc[i][j] = 0.f;

  for (int kt = 0; kt < F; kt += 32) {
    __syncthreads();
#pragma unroll
    for (int l = 0; l < 2; ++l) {
      const int idx = tid + l * 256;
      const int r = idx >> 3;
      const int j = idx & 7;
      const int grow = m0 + r;
      float4 v = make_float4(0.f, 0.f, 0.f, 0.f);
      if (grow < n) v = *(const float4*)(A + (size_t)grow * F + kt + j * 4);
      As[j * 4 + 0][r] = v.x;
      As[j * 4 + 1][r] = v.y;
      As[j * 4 + 2][r] = v.z;
      As[j * 4 + 3][r] = v.w;
    }
#pragma unroll
    for (int l = 0; l < 4; ++l) {
      const int idx = tid + l * 256;
      const int r = idx >> 3;
      const int j = idx & 7;
      const float4 v = *(const float4*)(W + (size_t)r * F + kt + j * 4);
      Bs[j * 4 + 0][r] = v.x;
      Bs[j * 4 + 1][r] = v.y;
      Bs[j * 4 + 2][r] = v.z;
      Bs[j * 4 + 3][r] = v.w;
    }
    __syncthreads();
#pragma unroll
    for (int k = 0; k < 32; ++k) {
      const float4 a0 = *(const float4*)&As[k][tm * 8];
      const float4 a1 = *(const float4*)&As[k][tm * 8 + 4];
      const float4 b = *(const float4*)&Bs[k][tn * 4];
      acc[0][0] += a0.x * b.x; acc[0][1] += a0.x * b.y; acc[0][2] += a0.x * b.z; acc[0][3] += a0.x * b.w;
      acc[1][0] += a0.y * b.x; acc[1][1] += a0.y * b.y; acc[1][2] += a0.y * b.z; acc[1][3] += a0.y * b.w;
      acc[2][0] += a0.z * b.x; acc[2][1] += a0.z * b.y; acc[2][2] += a0.z * b.z; acc[2][3] += a0.z * b.w;
      acc[3][0] += a0.w * b.x; acc[3][1] += a0.w * b.y; acc[3][2] += a0.w * b.z; acc[3][3] += a0.w * b.w;
      acc[4][0] += a1.x * b.x; acc[4][1] += a1.x * b.y; acc[4][2] += a1.x * b.z; acc[4][3] += a1.x * b.w;
      acc[5][0] += a1.y * b.x; acc[5][1] += a1.y * b.y; acc[5][2] += a1.y * b.z; acc[5][3] += a1.y * b.w;
      acc[6][0] += a1.z * b.x; acc[6][1] += a1.z * b.y; acc[6][2] += a1.z * b.z; acc[6][3] += a1.z * b.w;
      acc[7][0] += a1.w * b.x; acc[7][1] += a1.w * b.y; acc[7][2] += a1.w * b.z; acc[7][3] += a1.w * b.w;
    }
  }

  const float4 bv = *(const float4*)(bias + tn * 4);
#pragma unroll
  for (int i = 0; i < 8; ++i) {
    const int grow = m0 + tm * 8 + i;
    if (grow < n) {
      const float dv = dinv[grow];
      const float ox = (acc[i][0] + bv.x) * dv;
      const float oy = (acc[i][1] + bv.y) * dv;
      const float oz = (acc[i][2] + bv.z) * dv;
      const float ow = (acc[i][3] + bv.w) * dv;
      uint2 p;
      p.x = f2b(ox) | (f2b(oy) << 16);
      p.y = f2b(oz) | (f2b(ow) << 16);
      hout[(size_t)grow * 32 + tn] = p;  // 32 uint2 (=128 bf16) per row
    }
  }
}

// push aggregation: block per 64-node dst range, 64x128 f32 LDS accumulator.
// edges arrive src-bucket-sorted -> all co-resident blocks sweep hbuf in
// ascending order (shared L2 window). One wave per edge (lane = 2 bf16).
template <bool RELU>
__global__ __launch_bounds__(256) void k_push(
    const unsigned* __restrict__ csr2, const int* __restrict__ rbase,
    const unsigned* __restrict__ hb, const float* __restrict__ dinv,
    float* __restrict__ out, int N) {
  __shared__ float acc[NR][F];  // 32 KB
  const int r = blockIdx.x;
  const int tid = threadIdx.x;
  const int b = rbase[r];
  const int e = rbase[r + 1];
  const int node0 = r * NR;

  // init with self-loop h'[node]
  for (int idx = tid; idx < NR * 64; idx += 256) {
    const int row = idx >> 6;
    const int cu = idx & 63;
    const int node = node0 + row;
    const unsigned u = (node < N) ? hb[(size_t)node * 64 + cu] : 0u;
    acc[row][cu * 2] = b_lo(u);
    acc[row][cu * 2 + 1] = b_hi(u);
  }
  __syncthreads();

  const int wave = tid >> 6;
  const int lane = tid & 63;
  int k = b + wave;
  for (; k + 12 < e; k += 16) {
    const unsigned v0 = csr2[k];
    const unsigned v1 = csr2[k + 4];
    const unsigned v2 = csr2[k + 8];
    const unsigned v3 = csr2[k + 12];
    const unsigned u0 = hb[(size_t)(v0 & 0xffffu) * 64 + lane];
    const unsigned u1 = hb[(size_t)(v1 & 0xffffu) * 64 + lane];
    const unsigned u2 = hb[(size_t)(v2 & 0xffffu) * 64 + lane];
    const unsigned u3 = hb[(size_t)(v3 & 0xffffu) * 64 + lane];
    atomicAdd(&acc[v0 >> 16][lane * 2], b_lo(u0));
    atomicAdd(&acc[v0 >> 16][lane * 2 + 1], b_hi(u0));
    atomicAdd(&acc[v1 >> 16][lane * 2], b_lo(u1));
    atomicAdd(&acc[v1 >> 16][lane * 2 + 1], b_hi(u1));
    atomicAdd(&acc[v2 >> 16][lane * 2], b_lo(u2));
    atomicAdd(&acc[v2 >> 16][lane * 2 + 1], b_hi(u2));
    atomicAdd(&acc[v3 >> 16][lane * 2], b_lo(u3));
    atomicAdd(&acc[v3 >> 16][lane * 2 + 1], b_hi(u3));
  }
  for (; k < e; k += 4) {
    const unsigned v = csr2[k];
    const unsigned u = hb[(size_t)(v & 0xffffu) * 64 + lane];
    atomicAdd(&acc[v >> 16][lane * 2], b_lo(u));
    atomicAdd(&acc[v >> 16][lane * 2 + 1], b_hi(u));
  }
  __syncthreads();

  // epilogue: scale by dinv (+relu), float4 store
  for (int idx = tid; idx < NR * 32; idx += 256) {
    const int row = idx >> 5;
    const int q = idx & 31;
    const int node = node0 + row;
    if (node < N) {
      const float dv = dinv[node];
      float4 o;
      o.x = acc[row][q * 4 + 0] * dv;
      o.y = acc[row][q * 4 + 1] * dv;
      o.z = acc[row][q * 4 + 2] * dv;
      o.w = acc[row][q * 4 + 3] * dv;
      if (RELU) {
        o.x = fmaxf(o.x, 0.f);
        o.y = fmaxf(o.y, 0.f);
        o.z = fmaxf(o.z, 0.f);
        o.w = fmaxf(o.w, 0.f);
      }
      *(float4*)(out + (size_t)node * F + q * 4) = o;
    }
  }
}

extern "C" void kernel_launch(void* const* d_in, const int* in_sizes, int n_in,
                              void* d_out, int out_size, void* d_ws, size_t ws_size,
                              hipStream_t stream) {
  const float* x  = (const float*)d_in[0];
  const int*   ei = (const int*)d_in[1];
  const float* W1 = (const float*)d_in[2];
  const float* b1 = (const float*)d_in[3];
  const float* W2 = (const float*)d_in[4];
  const float* b2 = (const float*)d_in[5];

  const int N = in_sizes[0] / F;  // 50000
  const int E = in_sizes[1] / 2;  // 1600000
  const int* src = ei;
  const int* dst = ei + E;
  const int R = (N + NR - 1) / NR;  // 782
  const int C = (E + CH - 1) / CH;  // 391

  char* ws = (char*)d_ws;
  int*      rtot    = (int*)(ws);
  int*      rbase   = (int*)(ws + (4u << 10));
  int*      gcur    = (int*)(ws + (8u << 10));
  float*    dinv    = (float*)(ws + (16u << 10));
  unsigned* rsorted = (unsigned*)(ws + (1u << 20));
  unsigned* csr2    = (unsigned*)(ws + (8u << 20));
  unsigned* hbuf    = (unsigned*)(ws + (16u << 20));  // N*F bf16
  float*    out     = (float*)d_out;  // also layer-1 aggregation buffer

  const int B = 256;
  const int gemmBlocks = (N + 63) / 64;  // 782

  // build: range-sort by dst, then src-bucket-sort per range (+dinv)
  k_zero_i32<<<(R + 255) / 256, B, 0, stream>>>(rtot, R);
  k_hist<<<C, B, 0, stream>>>(dst, E, R, rtot);
  k_scanR<<<1, 1024, 0, stream>>>(rtot, R, E, rbase, gcur);
  k_part<<<C, B, 0, stream>>>(src, dst, E, R, gcur, rsorted);
  k_sortR<<<R, B, 0, stream>>>(rsorted, rbase, N, dinv, csr2);

  // layer 1
  k_gemm<<<gemmBlocks, B, 0, stream>>>(x, W1, b1, dinv, (uint2*)hbuf, N);
  k_push<true><<<R, B, 0, stream>>>(csr2, rbase, hbuf, dinv, out, N);

  // layer 2
  k_gemm<<<gemmBlocks, B, 0, stream>>>(out, W2, b2, dinv, (uint2*)hbuf, N);
  k_push<false><<<R, B, 0, stream>>>(csr2, rbase, hbuf, dinv, out, N);
}

// Round 8
// 301.070 us; speedup vs baseline: 9.3818x; 9.3818x over previous
//
#include <hip/hip_runtime.h>

// GCN 2-layer forward, N=50000, F=128, E=1.6M (+ self loops).
//
//   h'   = (x @ W^T + b) * dinv[row]        (stored bf16 -> halves gather bytes)
//   out  = dinv[row] * (h'[row] + sum_{e: dst=row} h'[src[e]])   (+ relu L1)
//
// CSR built via two-level counting sort (LDS atomics only, coalesced writes).
// Pull-mode aggregation: wave per node, two edges per step via half-wave
// uint2 (4xbf16) gathers, f32 accumulation, shfl_xor(32) combine.
// GEMM: MFMA bf16x3 (A=Ahi+Alo, W=Whi+Wlo; hi*hi+hi*lo+lo*hi) -> error ~2^-17,
// f32-equivalent precision at matrix-core rate. W pre-split once (L2-resident);
// A split in-register during fragment load. No LDS in the GEMM.
//
// ws layout:
//   [0]     rtot    R i32
//   [4K]    rbase   R+1 i32
//   [8K]    gcur    R i32
//   [16K]   dinv    N f32    (200 KB)
//   [256K]  rowptr  N+1 i32
//   [480K]  Whi1/Wlo1/Whi2/Wlo2  4x 32KB bf16
//   [1M]    rsorted E u32    (6.4 MB)
//   [8M]    csr     E i32    (6.4 MB)
//   [16M]   hbuf    N*F bf16 (12.8 MB)
// d_out doubles as the layer-1 aggregation output (fully overwritten later).

static constexpr int F = 128;
static constexpr int NR = 128;   // nodes per range (dst>>7)
static constexpr int CH = 4096;  // edges per chunk
static constexpr int RMAX = 512; // max ranges supported (N < 65536)

typedef __attribute__((ext_vector_type(8))) short bf16x8;
typedef __attribute__((ext_vector_type(4))) float f32x4;
typedef __attribute__((ext_vector_type(4))) unsigned short u16x4;

__device__ __forceinline__ unsigned f2b(float x) {  // f32 -> bf16 bits, RNE
  unsigned u = __float_as_uint(x);
  return (u + 0x7fffu + ((u >> 16) & 1u)) >> 16;
}
__device__ __forceinline__ float b_lo(unsigned u) {
  return __uint_as_float(u << 16);
}
__device__ __forceinline__ float b_hi(unsigned u) {
  return __uint_as_float(u & 0xffff0000u);
}

__global__ void k_zero_i32(int* __restrict__ p, int n) {
  int i = blockIdx.x * blockDim.x + threadIdx.x;
  if (i < n) p[i] = 0;
}

__global__ __launch_bounds__(256) void k_hist(const int* __restrict__ dst,
                                              int E, int R,
                                              int* __restrict__ rtot) {
  __shared__ int h[RMAX];
  for (int i = threadIdx.x; i < R; i += 256) h[i] = 0;
  __syncthreads();
  const int e0 = blockIdx.x * CH;
  const int e1 = min(e0 + CH, E);
  for (int i = e0 + threadIdx.x; i < e1; i += 256)
    atomicAdd(&h[dst[i] >> 7], 1);
  __syncthreads();
  for (int i = threadIdx.x; i < R; i += 256)
    if (h[i]) atomicAdd(&rtot[i], h[i]);
}

__global__ __launch_bounds__(512) void k_scanR(const int* __restrict__ rtot,
                                               int R, int E,
                                               int* __restrict__ rbase,
                                               int* __restrict__ gcur) {
  __shared__ int s[512];
  const int t = threadIdx.x;
  const int v = (t < R) ? rtot[t] : 0;
  s[t] = v;
  __syncthreads();
#pragma unroll
  for (int off = 1; off < 512; off <<= 1) {
    int a = (t >= off) ? s[t - off] : 0;
    __syncthreads();
    s[t] += a;
    __syncthreads();
  }
  if (t < R) {
    const int b = s[t] - v;  // exclusive
    rbase[t] = b;
    gcur[t] = b;
  }
  if (t == 0) rbase[R] = E;
}

__global__ __launch_bounds__(256) void k_part(const int* __restrict__ src,
                                              const int* __restrict__ dst,
                                              int E, int R,
                                              int* __restrict__ gcur,
                                              unsigned* __restrict__ rsorted) {
  __shared__ int h[RMAX];
  __shared__ int cur[RMAX];
  for (int i = threadIdx.x; i < R; i += 256) h[i] = 0;
  __syncthreads();
  const int e0 = blockIdx.x * CH;
  const int e1 = min(e0 + CH, E);
  for (int i = e0 + threadIdx.x; i < e1; i += 256)
    atomicAdd(&h[dst[i] >> 7], 1);
  __syncthreads();
  for (int i = threadIdx.x; i < R; i += 256)
    cur[i] = h[i] ? atomicAdd(&gcur[i], h[i]) : 0;
  __syncthreads();
  for (int i = e0 + threadIdx.x; i < e1; i += 256) {
    const int d = dst[i];
    const int s = src[i];
    const int pos = atomicAdd(&cur[d >> 7], 1);
    rsorted[pos] = ((unsigned)(d & (NR - 1)) << 16) | (unsigned)s;
  }
}

__global__ __launch_bounds__(256) void k_fillR(
    const unsigned* __restrict__ rsorted, const int* __restrict__ rbase,
    int N, int E, int* __restrict__ rowptr, float* __restrict__ dinv,
    int* __restrict__ csr) {
  __shared__ int cnt[NR];
  __shared__ int sc[NR];
  __shared__ int cur[NR];
  const int r = blockIdx.x;
  const int tid = threadIdx.x;
  const int b = rbase[r];
  const int e = rbase[r + 1];
  if (tid < NR) cnt[tid] = 0;
  __syncthreads();
  for (int i = b + tid; i < e; i += 256)
    atomicAdd(&cnt[rsorted[i] >> 16], 1);
  __syncthreads();
  if (tid < NR) sc[tid] = cnt[tid];
  __syncthreads();
#pragma unroll
  for (int off = 1; off < NR; off <<= 1) {
    int a = (tid < NR && tid >= off) ? sc[tid - off] : 0;
    __syncthreads();
    if (tid < NR) sc[tid] += a;
    __syncthreads();
  }
  if (tid < NR) {
    const int excl = sc[tid] - cnt[tid];
    cur[tid] = excl;
    const int node = r * NR + tid;
    if (node < N) {
      rowptr[node] = b + excl;
      dinv[node] = rsqrtf((float)(cnt[tid] + 1));  // +1 self loop
    }
  }
  if (r == 0 && tid == 0) rowptr[N] = E;
  __syncthreads();
  for (int i = b + tid; i < e; i += 256) {
    const unsigned v = rsorted[i];
    const int pos = b + atomicAdd(&cur[v >> 16], 1);
    csr[pos] = (int)(v & 0xFFFFu);
  }
}

// split W (128x128 f32) into bf16 hi/lo arrays (bf16x3 decomposition)
__global__ __launch_bounds__(256) void k_splitW(const float* __restrict__ W,
                                                unsigned short* __restrict__ hi,
                                                unsigned short* __restrict__ lo) {
  const int i = blockIdx.x * 256 + threadIdx.x;  // 16384 elems
  const float x = W[i];
  const unsigned h = f2b(x);
  hi[i] = (unsigned short)h;
  lo[i] = (unsigned short)f2b(x - __uint_as_float(h << 16));
}

// hout[m,:] = bf16( (A[m,:] @ W^T + bias) * dinv[m] )
// MFMA 16x16x32 bf16, bf16x3: acc += Ahi*Whi + Ahi*Wlo + Alo*Whi.
// Wave computes 16 rows x 128 cols; block = 4 waves = 64 rows. No LDS.
// k-slot map (4g+j / 16+4g+j) applied identically to A and B operands, so
// the true HW k-permutation cancels in the dot product.
__global__ __launch_bounds__(256) void k_gemm_mfma(
    const float* __restrict__ A, const unsigned short* __restrict__ Whi,
    const unsigned short* __restrict__ Wlo, const float* __restrict__ bias,
    const float* __restrict__ dinv, unsigned short* __restrict__ hout, int n) {
  const int wid = threadIdx.x >> 6;
  const int lane = threadIdx.x & 63;
  const int r = lane & 15;   // A row within tile / D col within frag
  const int g = lane >> 4;   // k-group
  const int m0 = blockIdx.x * 64 + wid * 16;
  const int arow = m0 + r;

  f32x4 acc[8];
#pragma unroll
  for (int f = 0; f < 8; ++f) acc[f] = (f32x4){0.f, 0.f, 0.f, 0.f};

#pragma unroll
  for (int kt = 0; kt < F; kt += 32) {
    float4 a0 = make_float4(0.f, 0.f, 0.f, 0.f);
    float4 a1 = make_float4(0.f, 0.f, 0.f, 0.f);
    if (arow < n) {
      a0 = *(const float4*)(A + (size_t)arow * F + kt + 4 * g);
      a1 = *(const float4*)(A + (size_t)arow * F + kt + 16 + 4 * g);
    }
    bf16x8 ahi, alo;
    {
      unsigned h;
      h = f2b(a0.x); ahi[0] = (short)h; alo[0] = (short)f2b(a0.x - __uint_as_float(h << 16));
      h = f2b(a0.y); ahi[1] = (short)h; alo[1] = (short)f2b(a0.y - __uint_as_float(h << 16));
      h = f2b(a0.z); ahi[2] = (short)h; alo[2] = (short)f2b(a0.z - __uint_as_float(h << 16));
      h = f2b(a0.w); ahi[3] = (short)h; alo[3] = (short)f2b(a0.w - __uint_as_float(h << 16));
      h = f2b(a1.x); ahi[4] = (short)h; alo[4] = (short)f2b(a1.x - __uint_as_float(h << 16));
      h = f2b(a1.y); ahi[5] = (short)h; alo[5] = (short)f2b(a1.y - __uint_as_float(h << 16));
      h = f2b(a1.z); ahi[6] = (short)h; alo[6] = (short)f2b(a1.z - __uint_as_float(h << 16));
      h = f2b(a1.w); ahi[7] = (short)h; alo[7] = (short)f2b(a1.w - __uint_as_float(h << 16));
    }
#pragma unroll
    for (int f = 0; f < 8; ++f) {
      const int col = f * 16 + r;
      const size_t wb = (size_t)col * F + kt + 4 * g;
      const u16x4 h0 = *(const u16x4*)(Whi + wb);
      const u16x4 h1 = *(const u16x4*)(Whi + wb + 16);
      const u16x4 l0 = *(const u16x4*)(Wlo + wb);
      const u16x4 l1 = *(const u16x4*)(Wlo + wb + 16);
      bf16x8 bhi, blo;
      bhi[0] = (short)h0[0]; bhi[1] = (short)h0[1]; bhi[2] = (short)h0[2]; bhi[3] = (short)h0[3];
      bhi[4] = (short)h1[0]; bhi[5] = (short)h1[1]; bhi[6] = (short)h1[2]; bhi[7] = (short)h1[3];
      blo[0] = (short)l0[0]; blo[1] = (short)l0[1]; blo[2] = (short)l0[2]; blo[3] = (short)l0[3];
      blo[4] = (short)l1[0]; blo[5] = (short)l1[1]; blo[6] = (short)l1[2]; blo[7] = (short)l1[3];
      acc[f] = __builtin_amdgcn_mfma_f32_16x16x32_bf16(ahi, bhi, acc[f], 0, 0, 0);
      acc[f] = __builtin_amdgcn_mfma_f32_16x16x32_bf16(ahi, blo, acc[f], 0, 0, 0);
      acc[f] = __builtin_amdgcn_mfma_f32_16x16x32_bf16(alo, bhi, acc[f], 0, 0, 0);
    }
  }

  // D layout (m89-verified): col = lane&15 (+16f), row = m0 + 4*(lane>>4) + j
  int orow[4];
  float dv[4];
#pragma unroll
  for (int j = 0; j < 4; ++j) {
    orow[j] = m0 + 4 * g + j;
    dv[j] = (orow[j] < n) ? dinv[orow[j]] : 0.f;
  }
#pragma unroll
  for (int f = 0; f < 8; ++f) {
    const int col = f * 16 + r;
    const float bv = bias[col];
#pragma unroll
    for (int j = 0; j < 4; ++j) {
      if (orow[j] < n)
        hout[(size_t)orow[j] * F + col] = (unsigned short)f2b((acc[f][j] + bv) * dv[j]);
    }
  }
}

// one 64-lane wave per node; two edges per step via half-wave uint2 gathers
// (4 bf16 per lane). lanes 0..31: edges beg,beg+2,...; lanes 32..63: beg+1,...
template <bool RELU>
__global__ __launch_bounds__(256) void k_pull(
    const int* __restrict__ rowptr, const int* __restrict__ csr,
    const uint2* __restrict__ h, const float* __restrict__ dinv,
    float* __restrict__ out, int n) {
  const int wid = (blockIdx.x * blockDim.x + threadIdx.x) >> 6;
  if (wid >= n) return;
  const int lane = threadIdx.x & 63;
  const int half = lane >> 5;
  const int l32 = lane & 31;
  const int beg = rowptr[wid];
  const int end = rowptr[wid + 1];

  float4 acc = make_float4(0.f, 0.f, 0.f, 0.f);
  if (half == 0) {  // self loop on half 0
    const uint2 u = h[(size_t)wid * 32 + l32];
    acc.x = b_lo(u.x); acc.y = b_hi(u.x);
    acc.z = b_lo(u.y); acc.w = b_hi(u.y);
  }

  int k = beg + half;
  // 4-deep unroll: 8 row-gathers in flight per wave
  for (; k + 6 < end; k += 8) {
    const int s0 = csr[k];
    const int s1 = csr[k + 2];
    const int s2 = csr[k + 4];
    const int s3 = csr[k + 6];
    const uint2 u0 = h[(size_t)s0 * 32 + l32];
    const uint2 u1 = h[(size_t)s1 * 32 + l32];
    const uint2 u2 = h[(size_t)s2 * 32 + l32];
    const uint2 u3 = h[(size_t)s3 * 32 + l32];
    acc.x += b_lo(u0.x) + b_lo(u1.x) + b_lo(u2.x) + b_lo(u3.x);
    acc.y += b_hi(u0.x) + b_hi(u1.x) + b_hi(u2.x) + b_hi(u3.x);
    acc.z += b_lo(u0.y) + b_lo(u1.y) + b_lo(u2.y) + b_lo(u3.y);
    acc.w += b_hi(u0.y) + b_hi(u1.y) + b_hi(u2.y) + b_hi(u3.y);
  }
  for (; k < end; k += 2) {
    const uint2 u = h[(size_t)csr[k] * 32 + l32];
    acc.x += b_lo(u.x);
    acc.y += b_hi(u.x);
    acc.z += b_lo(u.y);
    acc.w += b_hi(u.y);
  }

  // combine halves (lane L <-> lane L^32 hold the same 4 columns)
  acc.x += __shfl_xor(acc.x, 32, 64);
  acc.y += __shfl_xor(acc.y, 32, 64);
  acc.z += __shfl_xor(acc.z, 32, 64);
  acc.w += __shfl_xor(acc.w, 32, 64);

  if (half == 0) {
    const float dv = dinv[wid];
    float4 r;
    r.x = acc.x * dv;
    r.y = acc.y * dv;
    r.z = acc.z * dv;
    r.w = acc.w * dv;
    if (RELU) {
      r.x = fmaxf(r.x, 0.f);
      r.y = fmaxf(r.y, 0.f);
      r.z = fmaxf(r.z, 0.f);
      r.w = fmaxf(r.w, 0.f);
    }
    ((float4*)out)[(size_t)wid * 32 + l32] = r;
  }
}

extern "C" void kernel_launch(void* const* d_in, const int* in_sizes, int n_in,
                              void* d_out, int out_size, void* d_ws, size_t ws_size,
                              hipStream_t stream) {
  const float* x  = (const float*)d_in[0];
  const int*   ei = (const int*)d_in[1];
  const float* W1 = (const float*)d_in[2];
  const float* b1 = (const float*)d_in[3];
  const float* W2 = (const float*)d_in[4];
  const float* b2 = (const float*)d_in[5];

  const int N = in_sizes[0] / F;  // 50000
  const int E = in_sizes[1] / 2;  // 1600000
  const int* src = ei;
  const int* dst = ei + E;
  const int R = (N + NR - 1) / NR;  // 391
  const int C = (E + CH - 1) / CH;  // 391

  char* ws = (char*)d_ws;
  int*            rtot    = (int*)(ws);
  int*            rbase   = (int*)(ws + (4u << 10));
  int*            gcur    = (int*)(ws + (8u << 10));
  float*          dinv    = (float*)(ws + (16u << 10));
  int*            rowptr  = (int*)(ws + (256u << 10));
  unsigned short* Whi1    = (unsigned short*)(ws + (480u << 10));
  unsigned short* Wlo1    = (unsigned short*)(ws + (512u << 10));
  unsigned short* Whi2    = (unsigned short*)(ws + (544u << 10));
  unsigned short* Wlo2    = (unsigned short*)(ws + (576u << 10));
  unsigned*       rsorted = (unsigned*)(ws + (1u << 20));
  int*            csr     = (int*)(ws + (8u << 20));
  unsigned short* hbuf    = (unsigned short*)(ws + (16u << 20));  // N*F bf16
  float*          out     = (float*)d_out;  // also layer-1 aggregation buffer

  const int B = 256;
  const int gemmBlocks = (N + 63) / 64;         // 782
  const int pullBlocks = (N * 64 + B - 1) / B;  // 12500

  // CSR build (counting sort, LDS atomics only) + W split
  k_zero_i32<<<(R + 255) / 256, B, 0, stream>>>(rtot, R);
  k_hist<<<C, B, 0, stream>>>(dst, E, R, rtot);
  k_scanR<<<1, 512, 0, stream>>>(rtot, R, E, rbase, gcur);
  k_part<<<C, B, 0, stream>>>(src, dst, E, R, gcur, rsorted);
  k_fillR<<<R, B, 0, stream>>>(rsorted, rbase, N, E, rowptr, dinv, csr);
  k_splitW<<<64, B, 0, stream>>>(W1, Whi1, Wlo1);
  k_splitW<<<64, B, 0, stream>>>(W2, Whi2, Wlo2);

  // layer 1
  k_gemm_mfma<<<gemmBlocks, B, 0, stream>>>(x, Whi1, Wlo1, b1, dinv, hbuf, N);
  k_pull<true><<<pullBlocks, B, 0, stream>>>(rowptr, csr, (const uint2*)hbuf, dinv, out, N);

  // layer 2
  k_gemm_mfma<<<gemmBlocks, B, 0, stream>>>(out, Whi2, Wlo2, b2, dinv, hbuf, N);
  k_pull<false><<<pullBlocks, B, 0, stream>>>(rowptr, csr, (const uint2*)hbuf, dinv, out, N);
}

// Round 9
// 214.875 us; speedup vs baseline: 13.1451x; 1.4011x over previous
//
#include <hip/hip_runtime.h>

// GCN 2-layer forward, N=50000, F=128, E=1.6M (+ self loops).
//
//   h'   = (x @ W^T + b) * dinv[row]        (stored bf16 -> halves gather bytes)
//   out  = dinv[row] * (h'[row] + sum_{e: dst=row} h'[src[e]])   (+ relu L1)
//
// CSR built via two-level counting sort (LDS atomics only, coalesced writes).
// Pull-mode aggregation: wave per node, two edges per step via half-wave
// uint2 (4xbf16) gathers, f32 accumulation, shfl_xor(32) combine.
// GEMM: MFMA bf16x3 (A=Ahi+Alo, W=Whi+Wlo; hi*hi+hi*lo+lo*hi) -> error ~2^-17.
// W pre-split into FRAGMENT-MAJOR layout Wf[t][f][lane][8] so the GEMM's wave
// loads are one coalesced b128 per fragment (same addr across blocks -> L2
// broadcast); fragments for each k-tile hoisted into registers and reused.
//
// ws layout:
//   [0]     rtot    R i32
//   [4K]    rbase   R+1 i32
//   [8K]    gcur    R i32
//   [16K]   dinv    N f32    (200 KB)
//   [256K]  rowptr  N+1 i32
//   [480K]  Whi1/Wlo1/Whi2/Wlo2  4x 32KB bf16 (fragment-major)
//   [1M]    rsorted E u32    (6.4 MB)
//   [8M]    csr     E i32    (6.4 MB)
//   [16M]   hbuf    N*F bf16 (12.8 MB)
// d_out doubles as the layer-1 aggregation output (fully overwritten later).

static constexpr int F = 128;
static constexpr int NR = 128;   // nodes per range (dst>>7)
static constexpr int CH = 4096;  // edges per chunk
static constexpr int RMAX = 512; // max ranges supported (N < 65536)

typedef __attribute__((ext_vector_type(8))) short bf16x8;
typedef __attribute__((ext_vector_type(4))) float f32x4;

__device__ __forceinline__ unsigned f2b(float x) {  // f32 -> bf16 bits, RNE
  unsigned u = __float_as_uint(x);
  return (u + 0x7fffu + ((u >> 16) & 1u)) >> 16;
}
__device__ __forceinline__ float b_lo(unsigned u) {
  return __uint_as_float(u << 16);
}
__device__ __forceinline__ float b_hi(unsigned u) {
  return __uint_as_float(u & 0xffff0000u);
}

__global__ void k_zero_i32(int* __restrict__ p, int n) {
  int i = blockIdx.x * blockDim.x + threadIdx.x;
  if (i < n) p[i] = 0;
}

__global__ __launch_bounds__(256) void k_hist(const int* __restrict__ dst,
                                              int E, int R,
                                              int* __restrict__ rtot) {
  __shared__ int h[RMAX];
  for (int i = threadIdx.x; i < R; i += 256) h[i] = 0;
  __syncthreads();
  const int e0 = blockIdx.x * CH;
  const int e1 = min(e0 + CH, E);
  for (int i = e0 + threadIdx.x; i < e1; i += 256)
    atomicAdd(&h[dst[i] >> 7], 1);
  __syncthreads();
  for (int i = threadIdx.x; i < R; i += 256)
    if (h[i]) atomicAdd(&rtot[i], h[i]);
}

__global__ __launch_bounds__(512) void k_scanR(const int* __restrict__ rtot,
                                               int R, int E,
                                               int* __restrict__ rbase,
                                               int* __restrict__ gcur) {
  __shared__ int s[512];
  const int t = threadIdx.x;
  const int v = (t < R) ? rtot[t] : 0;
  s[t] = v;
  __syncthreads();
#pragma unroll
  for (int off = 1; off < 512; off <<= 1) {
    int a = (t >= off) ? s[t - off] : 0;
    __syncthreads();
    s[t] += a;
    __syncthreads();
  }
  if (t < R) {
    const int b = s[t] - v;  // exclusive
    rbase[t] = b;
    gcur[t] = b;
  }
  if (t == 0) rbase[R] = E;
}

__global__ __launch_bounds__(256) void k_part(const int* __restrict__ src,
                                              const int* __restrict__ dst,
                                              int E, int R,
                                              int* __restrict__ gcur,
                                              unsigned* __restrict__ rsorted) {
  __shared__ int h[RMAX];
  __shared__ int cur[RMAX];
  for (int i = threadIdx.x; i < R; i += 256) h[i] = 0;
  __syncthreads();
  const int e0 = blockIdx.x * CH;
  const int e1 = min(e0 + CH, E);
  for (int i = e0 + threadIdx.x; i < e1; i += 256)
    atomicAdd(&h[dst[i] >> 7], 1);
  __syncthreads();
  for (int i = threadIdx.x; i < R; i += 256)
    cur[i] = h[i] ? atomicAdd(&gcur[i], h[i]) : 0;
  __syncthreads();
  for (int i = e0 + threadIdx.x; i < e1; i += 256) {
    const int d = dst[i];
    const int s = src[i];
    const int pos = atomicAdd(&cur[d >> 7], 1);
    rsorted[pos] = ((unsigned)(d & (NR - 1)) << 16) | (unsigned)s;
  }
}

__global__ __launch_bounds__(256) void k_fillR(
    const unsigned* __restrict__ rsorted, const int* __restrict__ rbase,
    int N, int E, int* __restrict__ rowptr, float* __restrict__ dinv,
    int* __restrict__ csr) {
  __shared__ int cnt[NR];
  __shared__ int sc[NR];
  __shared__ int cur[NR];
  const int r = blockIdx.x;
  const int tid = threadIdx.x;
  const int b = rbase[r];
  const int e = rbase[r + 1];
  if (tid < NR) cnt[tid] = 0;
  __syncthreads();
  for (int i = b + tid; i < e; i += 256)
    atomicAdd(&cnt[rsorted[i] >> 16], 1);
  __syncthreads();
  if (tid < NR) sc[tid] = cnt[tid];
  __syncthreads();
#pragma unroll
  for (int off = 1; off < NR; off <<= 1) {
    int a = (tid < NR && tid >= off) ? sc[tid - off] : 0;
    __syncthreads();
    if (tid < NR) sc[tid] += a;
    __syncthreads();
  }
  if (tid < NR) {
    const int excl = sc[tid] - cnt[tid];
    cur[tid] = excl;
    const int node = r * NR + tid;
    if (node < N) {
      rowptr[node] = b + excl;
      dinv[node] = rsqrtf((float)(cnt[tid] + 1));  // +1 self loop
    }
  }
  if (r == 0 && tid == 0) rowptr[N] = E;
  __syncthreads();
  for (int i = b + tid; i < e; i += 256) {
    const unsigned v = rsorted[i];
    const int pos = b + atomicAdd(&cur[v >> 16], 1);
    csr[pos] = (int)(v & 0xFFFFu);
  }
}

// split W (128x128 f32) into bf16 hi/lo in FRAGMENT-MAJOR layout:
//   Wf[t][f][lane][j] = W[16f + (lane&15)][32t + (j<4?0:16) + 4*(lane>>4) + (j&3)]
// so a wave's b128 load of fragment (t,f) is fully coalesced.
__global__ __launch_bounds__(256) void k_splitW(const float* __restrict__ W,
                                                unsigned short* __restrict__ hi,
                                                unsigned short* __restrict__ lo) {
  const int i = blockIdx.x * 256 + threadIdx.x;  // 16384 elems
  const int j = i & 7;
  const int lane = (i >> 3) & 63;
  const int f = (i >> 9) & 7;
  const int t = i >> 12;
  const int col = f * 16 + (lane & 15);
  const int k = t * 32 + ((j & 4) << 2) + 4 * (lane >> 4) + (j & 3);
  const float x = W[col * F + k];
  const unsigned h = f2b(x);
  hi[i] = (unsigned short)h;
  lo[i] = (unsigned short)f2b(x - __uint_as_float(h << 16));
}

// hout[m,:] = bf16( (A[m,:] @ W^T + bias) * dinv[m] )
// MFMA 16x16x32 bf16, bf16x3: acc += Ahi*Whi + Ahi*Wlo + Alo*Whi.
// Wave computes 16 rows x 128 cols; block = 4 waves = 64 rows. No LDS.
// W fragments hoisted per k-tile (coalesced b128 from fragment-major buffer).
__global__ __launch_bounds__(256) void k_gemm_mfma(
    const float* __restrict__ A, const unsigned short* __restrict__ Whi,
    const unsigned short* __restrict__ Wlo, const float* __restrict__ bias,
    const float* __restrict__ dinv, unsigned short* __restrict__ hout, int n) {
  const int wid = threadIdx.x >> 6;
  const int lane = threadIdx.x & 63;
  const int r = lane & 15;   // A row within tile / D col within frag
  const int g = lane >> 4;   // k-group
  const int m0 = blockIdx.x * 64 + wid * 16;
  const int arow = m0 + r;

  f32x4 acc[8];
#pragma unroll
  for (int f = 0; f < 8; ++f) acc[f] = (f32x4){0.f, 0.f, 0.f, 0.f};

#pragma unroll
  for (int t = 0; t < 4; ++t) {
    // hoist W fragments for this k-tile: 16 coalesced b128 loads
    bf16x8 bhi[8], blo[8];
#pragma unroll
    for (int f = 0; f < 8; ++f) {
      const size_t base = (((size_t)t * 8 + f) * 64 + lane) * 8;
      bhi[f] = *(const bf16x8*)(Whi + base);
      blo[f] = *(const bf16x8*)(Wlo + base);
    }
    // A fragment for this k-tile
    const int kt = t * 32;
    float4 a0 = make_float4(0.f, 0.f, 0.f, 0.f);
    float4 a1 = make_float4(0.f, 0.f, 0.f, 0.f);
    if (arow < n) {
      a0 = *(const float4*)(A + (size_t)arow * F + kt + 4 * g);
      a1 = *(const float4*)(A + (size_t)arow * F + kt + 16 + 4 * g);
    }
    bf16x8 ahi, alo;
    {
      unsigned h;
      h = f2b(a0.x); ahi[0] = (short)h; alo[0] = (short)f2b(a0.x - __uint_as_float(h << 16));
      h = f2b(a0.y); ahi[1] = (short)h; alo[1] = (short)f2b(a0.y - __uint_as_float(h << 16));
      h = f2b(a0.z); ahi[2] = (short)h; alo[2] = (short)f2b(a0.z - __uint_as_float(h << 16));
      h = f2b(a0.w); ahi[3] = (short)h; alo[3] = (short)f2b(a0.w - __uint_as_float(h << 16));
      h = f2b(a1.x); ahi[4] = (short)h; alo[4] = (short)f2b(a1.x - __uint_as_float(h << 16));
      h = f2b(a1.y); ahi[5] = (short)h; alo[5] = (short)f2b(a1.y - __uint_as_float(h << 16));
      h = f2b(a1.z); ahi[6] = (short)h; alo[6] = (short)f2b(a1.z - __uint_as_float(h << 16));
      h = f2b(a1.w); ahi[7] = (short)h; alo[7] = (short)f2b(a1.w - __uint_as_float(h << 16));
    }
#pragma unroll
    for (int f = 0; f < 8; ++f) {
      acc[f] = __builtin_amdgcn_mfma_f32_16x16x32_bf16(ahi, bhi[f], acc[f], 0, 0, 0);
      acc[f] = __builtin_amdgcn_mfma_f32_16x16x32_bf16(ahi, blo[f], acc[f], 0, 0, 0);
      acc[f] = __builtin_amdgcn_mfma_f32_16x16x32_bf16(alo, bhi[f], acc[f], 0, 0, 0);
    }
  }

  // D layout (m89-verified): col = 16f + (lane&15), row = m0 + 4*(lane>>4) + j
  int orow[4];
  float dv[4];
#pragma unroll
  for (int j = 0; j < 4; ++j) {
    orow[j] = m0 + 4 * g + j;
    dv[j] = (orow[j] < n) ? dinv[orow[j]] : 0.f;
  }
#pragma unroll
  for (int f = 0; f < 8; ++f) {
    const int col = f * 16 + r;
    const float bv = bias[col];
#pragma unroll
    for (int j = 0; j < 4; ++j) {
      if (orow[j] < n)
        hout[(size_t)orow[j] * F + col] = (unsigned short)f2b((acc[f][j] + bv) * dv[j]);
    }
  }
}

// one 64-lane wave per node; two edges per step via half-wave uint2 gathers
// (4 bf16 per lane). lanes 0..31: edges beg,beg+2,...; lanes 32..63: beg+1,...
template <bool RELU>
__global__ __launch_bounds__(256) void k_pull(
    const int* __restrict__ rowptr, const int* __restrict__ csr,
    const uint2* __restrict__ h, const float* __restrict__ dinv,
    float* __restrict__ out, int n) {
  const int wid = (blockIdx.x * blockDim.x + threadIdx.x) >> 6;
  if (wid >= n) return;
  const int lane = threadIdx.x & 63;
  const int half = lane >> 5;
  const int l32 = lane & 31;
  const int beg = rowptr[wid];
  const int end = rowptr[wid + 1];

  float4 acc = make_float4(0.f, 0.f, 0.f, 0.f);
  if (half == 0) {  // self loop on half 0
    const uint2 u = h[(size_t)wid * 32 + l32];
    acc.x = b_lo(u.x); acc.y = b_hi(u.x);
    acc.z = b_lo(u.y); acc.w = b_hi(u.y);
  }

  int k = beg + half;
  // 4-deep unroll: 8 row-gathers in flight per wave
  for (; k + 6 < end; k += 8) {
    const int s0 = csr[k];
    const int s1 = csr[k + 2];
    const int s2 = csr[k + 4];
    const int s3 = csr[k + 6];
    const uint2 u0 = h[(size_t)s0 * 32 + l32];
    const uint2 u1 = h[(size_t)s1 * 32 + l32];
    const uint2 u2 = h[(size_t)s2 * 32 + l32];
    const uint2 u3 = h[(size_t)s3 * 32 + l32];
    acc.x += b_lo(u0.x) + b_lo(u1.x) + b_lo(u2.x) + b_lo(u3.x);
    acc.y += b_hi(u0.x) + b_hi(u1.x) + b_hi(u2.x) + b_hi(u3.x);
    acc.z += b_lo(u0.y) + b_lo(u1.y) + b_lo(u2.y) + b_lo(u3.y);
    acc.w += b_hi(u0.y) + b_hi(u1.y) + b_hi(u2.y) + b_hi(u3.y);
  }
  for (; k < end; k += 2) {
    const uint2 u = h[(size_t)csr[k] * 32 + l32];
    acc.x += b_lo(u.x);
    acc.y += b_hi(u.x);
    acc.z += b_lo(u.y);
    acc.w += b_hi(u.y);
  }

  // combine halves (lane L <-> lane L^32 hold the same 4 columns)
  acc.x += __shfl_xor(acc.x, 32, 64);
  acc.y += __shfl_xor(acc.y, 32, 64);
  acc.z += __shfl_xor(acc.z, 32, 64);
  acc.w += __shfl_xor(acc.w, 32, 64);

  if (half == 0) {
    const float dv = dinv[wid];
    float4 r;
    r.x = acc.x * dv;
    r.y = acc.y * dv;
    r.z = acc.z * dv;
    r.w = acc.w * dv;
    if (RELU) {
      r.x = fmaxf(r.x, 0.f);
      r.y = fmaxf(r.y, 0.f);
      r.z = fmaxf(r.z, 0.f);
      r.w = fmaxf(r.w, 0.f);
    }
    ((float4*)out)[(size_t)wid * 32 + l32] = r;
  }
}

extern "C" void kernel_launch(void* const* d_in, const int* in_sizes, int n_in,
                              void* d_out, int out_size, void* d_ws, size_t ws_size,
                              hipStream_t stream) {
  const float* x  = (const float*)d_in[0];
  const int*   ei = (const int*)d_in[1];
  const float* W1 = (const float*)d_in[2];
  const float* b1 = (const float*)d_in[3];
  const float* W2 = (const float*)d_in[4];
  const float* b2 = (const float*)d_in[5];

  const int N = in_sizes[0] / F;  // 50000
  const int E = in_sizes[1] / 2;  // 1600000
  const int* src = ei;
  const int* dst = ei + E;
  const int R = (N + NR - 1) / NR;  // 391
  const int C = (E + CH - 1) / CH;  // 391

  char* ws = (char*)d_ws;
  int*            rtot    = (int*)(ws);
  int*            rbase   = (int*)(ws + (4u << 10));
  int*            gcur    = (int*)(ws + (8u << 10));
  float*          dinv    = (float*)(ws + (16u << 10));
  int*            rowptr  = (int*)(ws + (256u << 10));
  unsigned short* Whi1    = (unsigned short*)(ws + (480u << 10));
  unsigned short* Wlo1    = (unsigned short*)(ws + (512u << 10));
  unsigned short* Whi2    = (unsigned short*)(ws + (544u << 10));
  unsigned short* Wlo2    = (unsigned short*)(ws + (576u << 10));
  unsigned*       rsorted = (unsigned*)(ws + (1u << 20));
  int*            csr     = (int*)(ws + (8u << 20));
  unsigned short* hbuf    = (unsigned short*)(ws + (16u << 20));  // N*F bf16
  float*          out     = (float*)d_out;  // also layer-1 aggregation buffer

  const int B = 256;
  const int gemmBlocks = (N + 63) / 64;         // 782
  const int pullBlocks = (N * 64 + B - 1) / B;  // 12500

  // CSR build (counting sort, LDS atomics only) + W split (fragment-major)
  k_zero_i32<<<(R + 255) / 256, B, 0, stream>>>(rtot, R);
  k_hist<<<C, B, 0, stream>>>(dst, E, R, rtot);
  k_scanR<<<1, 512, 0, stream>>>(rtot, R, E, rbase, gcur);
  k_part<<<C, B, 0, stream>>>(src, dst, E, R, gcur, rsorted);
  k_fillR<<<R, B, 0, stream>>>(rsorted, rbase, N, E, rowptr, dinv, csr);
  k_splitW<<<64, B, 0, stream>>>(W1, Whi1, Wlo1);
  k_splitW<<<64, B, 0, stream>>>(W2, Whi2, Wlo2);

  // layer 1
  k_gemm_mfma<<<gemmBlocks, B, 0, stream>>>(x, Whi1, Wlo1, b1, dinv, hbuf, N);
  k_pull<true><<<pullBlocks, B, 0, stream>>>(rowptr, csr, (const uint2*)hbuf, dinv, out, N);

  // layer 2
  k_gemm_mfma<<<gemmBlocks, B, 0, stream>>>(out, Whi2, Wlo2, b2, dinv, hbuf, N);
  k_pull<false><<<pullBlocks, B, 0, stream>>>(rowptr, csr, (const uint2*)hbuf, dinv, out, N);
}